// Round 1
// baseline (129.565 us; speedup 1.0000x reference)
//
#include <hip/hip_runtime.h>

namespace {
constexpr int kB = 32;
constexpr int kS = 2048;
constexpr int kH = 1024;
constexpr int kD = 1024;
constexpr int kK2 = kH + kD;           // 2048
constexpr int kSChunk = 128;
constexpr int kNChunk = kS / kSChunk;  // 16

__device__ inline float waveReduceSum(float v) {
#pragma unroll
  for (int off = 32; off > 0; off >>= 1) v += __shfl_down(v, off, 64);
  return v;
}
__device__ inline float waveReduceMax(float v) {
#pragma unroll
  for (int off = 32; off > 0; off >>= 1) v = fmaxf(v, __shfl_down(v, off, 64));
  return v;
}
}  // namespace

// x = hidden @ W1^T : [B, D]. One wave per 2 output columns; W1 rows in regs.
__global__ __launch_bounds__(256) void k_x(const float* __restrict__ hidden,
                                           const float* __restrict__ W1,
                                           float* __restrict__ x) {
  const int wave = (blockIdx.x * blockDim.x + threadIdx.x) >> 6;  // 0..511
  const int lane = threadIdx.x & 63;
  const int n0 = wave * 2;
  const float4* w0v = (const float4*)(W1 + (size_t)n0 * kH);
  const float4* w1v = (const float4*)(W1 + (size_t)(n0 + 1) * kH);
  float4 w0[4], w1[4];
#pragma unroll
  for (int i = 0; i < 4; ++i) {
    w0[i] = w0v[lane + 64 * i];
    w1[i] = w1v[lane + 64 * i];
  }
  for (int b = 0; b < kB; ++b) {
    const float4* hv = (const float4*)(hidden + (size_t)b * kH);
    float a0 = 0.f, a1 = 0.f;
#pragma unroll
    for (int i = 0; i < 4; ++i) {
      const float4 h = hv[lane + 64 * i];
      a0 += w0[i].x * h.x + w0[i].y * h.y + w0[i].z * h.z + w0[i].w * h.w;
      a1 += w1[i].x * h.x + w1[i].y * h.y + w1[i].z * h.z + w1[i].w * h.w;
    }
    a0 = waveReduceSum(a0);
    a1 = waveReduceSum(a1);
    if (lane == 0) {
      x[(size_t)b * kD + n0] = a0;
      x[(size_t)b * kD + n0 + 1] = a1;
    }
  }
}

// att[b,s] = dot(enc[b,s,:], x[b,:]) for s < len[b]. Wave per 4 rows.
__global__ __launch_bounds__(256) void k_att(const float* __restrict__ enc,
                                             const float* __restrict__ x,
                                             const int* __restrict__ lens,
                                             float* __restrict__ att) {
  const int lane = threadIdx.x & 63;
  const int wib = threadIdx.x >> 6;
  const int b = blockIdx.x & 31;
  const int s0 = (blockIdx.x >> 5) * 16 + wib * 4;
  const int len = lens[b];
  if (s0 >= len) return;  // weight is exactly 0 -> never needed
  const float4* xv = (const float4*)(x + (size_t)b * kD);
  float4 xr[4];
#pragma unroll
  for (int i = 0; i < 4; ++i) xr[i] = xv[lane + 64 * i];
#pragma unroll
  for (int r = 0; r < 4; ++r) {
    const float4* ev = (const float4*)(enc + ((size_t)b * kS + (s0 + r)) * kD);
    float acc = 0.f;
#pragma unroll
    for (int i = 0; i < 4; ++i) {
      const float4 e = ev[lane + 64 * i];
      acc += xr[i].x * e.x + xr[i].y * e.y + xr[i].z * e.z + xr[i].w * e.w;
    }
    acc = waveReduceSum(acc);
    if (lane == 0) att[(size_t)b * kS + s0 + r] = acc;
  }
}

// Masked softmax per batch row, faithful to the ==0 -> -1e10 quirk.
// Writes attn^T into d_out, a coalesced [B][S] copy into ws, and s_count.
__global__ __launch_bounds__(256) void k_softmax(const float* __restrict__ att,
                                                 const int* __restrict__ lens,
                                                 float* __restrict__ attnT,
                                                 float* __restrict__ attn_bs,
                                                 int* __restrict__ s_count) {
  const int b = blockIdx.x;
  const int t = threadIdx.x;
  const int len = lens[b];
  __shared__ float sred[4];
  float v[8];
#pragma unroll
  for (int i = 0; i < 8; ++i) {
    const int s = t + i * 256;
    const float a = (s < len) ? att[(size_t)b * kS + s] : 0.0f;
    v[i] = (a == 0.0f) ? -1e10f : a;
  }
  float m = v[0];
#pragma unroll
  for (int i = 1; i < 8; ++i) m = fmaxf(m, v[i]);
  m = waveReduceMax(m);
  if ((t & 63) == 0) sred[t >> 6] = m;
  __syncthreads();
  m = fmaxf(fmaxf(sred[0], sred[1]), fmaxf(sred[2], sred[3]));
  __syncthreads();
  float p[8];
  float sum = 0.f;
#pragma unroll
  for (int i = 0; i < 8; ++i) {
    p[i] = __expf(v[i] - m);  // underflows to exactly 0 for masked rows
    sum += p[i];
  }
  sum = waveReduceSum(sum);
  if ((t & 63) == 0) sred[t >> 6] = sum;
  __syncthreads();
  const float inv = 1.0f / (sred[0] + sred[1] + sred[2] + sred[3]);
#pragma unroll
  for (int i = 0; i < 8; ++i) {
    const int s = t + i * 256;
    const float a = p[i] * inv;
    attnT[(size_t)s * kB + b] = a;          // output 1: attn^T [S][B]
    attn_bs[(size_t)b * kS + s] = a;        // coalesced copy for k_ctx
  }
  // degenerate case (all valid scores exactly 0): uniform over ALL S rows
  if (t == 0) s_count[b] = (m == -1e10f) ? kS : len;
}

// ctx partials: partial[c][b][:] = sum_{s in chunk c, s < cnt} w[s]*enc[b,s,:]
__global__ __launch_bounds__(256) void k_ctx(const float* __restrict__ enc,
                                             const float* __restrict__ attn_bs,
                                             const int* __restrict__ s_count,
                                             float* __restrict__ partial) {
  const int b = blockIdx.x & 31;
  const int c = blockIdx.x >> 5;
  const int s0 = c * kSChunk;
  const int cnt = s_count[b];
  if (s0 >= cnt) return;  // all weights in this chunk are exactly 0
  const int send = min(s0 + kSChunk, cnt);
  const int t = threadIdx.x;
  const float4* ev = (const float4*)(enc + ((size_t)b * kS + s0) * kD) + t;
  float4 acc = make_float4(0.f, 0.f, 0.f, 0.f);
  int s = s0;
  const int send4 = s0 + ((send - s0) & ~3);
  for (; s < send4; s += 4, ev += 1024) {
    const float4 w4 = *(const float4*)(attn_bs + (size_t)b * kS + s);
    const float4 e0 = ev[0], e1 = ev[256], e2 = ev[512], e3 = ev[768];
    acc.x += w4.x * e0.x + w4.y * e1.x + w4.z * e2.x + w4.w * e3.x;
    acc.y += w4.x * e0.y + w4.y * e1.y + w4.z * e2.y + w4.w * e3.y;
    acc.z += w4.x * e0.z + w4.y * e1.z + w4.z * e2.z + w4.w * e3.z;
    acc.w += w4.x * e0.w + w4.y * e1.w + w4.z * e2.w + w4.w * e3.w;
  }
  for (; s < send; ++s, ev += 256) {
    const float w = attn_bs[(size_t)b * kS + s];
    const float4 e = ev[0];
    acc.x += w * e.x; acc.y += w * e.y; acc.z += w * e.z; acc.w += w * e.w;
  }
  ((float4*)(partial + ((size_t)c * kB + b) * kD))[t] = acc;
}

// cat[b, 0:D] = sum of valid ctx partials; cat[b, D:D+H] = hidden[b,:]
__global__ __launch_bounds__(256) void k_cat(const float* __restrict__ partial,
                                             const float* __restrict__ hidden,
                                             const int* __restrict__ s_count,
                                             float* __restrict__ cat) {
  const int idx = blockIdx.x * 256 + threadIdx.x;  // float4 index into [B][K2]
  const int b = idx >> 9;   // 512 float4 per row
  const int j = idx & 511;
  float4* dst = (float4*)(cat + (size_t)b * kK2);
  if (j < 256) {
    const int nch = (s_count[b] + kSChunk - 1) / kSChunk;
    float4 acc = make_float4(0.f, 0.f, 0.f, 0.f);
    for (int c = 0; c < nch; ++c) {
      const float4 p = ((const float4*)(partial + ((size_t)c * kB + b) * kD))[j];
      acc.x += p.x; acc.y += p.y; acc.z += p.z; acc.w += p.w;
    }
    dst[j] = acc;
  } else {
    dst[j] = ((const float4*)(hidden + (size_t)b * kH))[j - 256];
  }
}

// out = tanh(cat @ W2^T) : [B, D]. One wave per 2 output columns.
__global__ __launch_bounds__(256) void k_out(const float* __restrict__ cat,
                                             const float* __restrict__ W2,
                                             float* __restrict__ out) {
  const int wave = (blockIdx.x * blockDim.x + threadIdx.x) >> 6;  // 0..511
  const int lane = threadIdx.x & 63;
  const int n0 = wave * 2;
  const float4* w0v = (const float4*)(W2 + (size_t)n0 * kK2);
  const float4* w1v = (const float4*)(W2 + (size_t)(n0 + 1) * kK2);
  float4 w0[8], w1[8];
#pragma unroll
  for (int i = 0; i < 8; ++i) {
    w0[i] = w0v[lane + 64 * i];
    w1[i] = w1v[lane + 64 * i];
  }
  for (int b = 0; b < kB; ++b) {
    const float4* av = (const float4*)(cat + (size_t)b * kK2);
    float a0 = 0.f, a1 = 0.f;
#pragma unroll
    for (int i = 0; i < 8; ++i) {
      const float4 a = av[lane + 64 * i];
      a0 += w0[i].x * a.x + w0[i].y * a.y + w0[i].z * a.z + w0[i].w * a.w;
      a1 += w1[i].x * a.x + w1[i].y * a.y + w1[i].z * a.z + w1[i].w * a.w;
    }
    a0 = waveReduceSum(a0);
    a1 = waveReduceSum(a1);
    if (lane == 0) {
      out[(size_t)b * kD + n0] = tanhf(a0);
      out[(size_t)b * kD + n0 + 1] = tanhf(a1);
    }
  }
}

extern "C" void kernel_launch(void* const* d_in, const int* in_sizes, int n_in,
                              void* d_out, int out_size, void* d_ws, size_t ws_size,
                              hipStream_t stream) {
  const float* hidden = (const float*)d_in[0];    // [B, H]
  const float* enc    = (const float*)d_in[1];    // [B, S, D]
  const int*   lens   = (const int*)d_in[2];      // [B]
  const float* W1     = (const float*)d_in[3];    // [D, H]
  const float* W2     = (const float*)d_in[4];    // [D, H+D]

  float* out   = (float*)d_out;                   // [B, D] = 32768 floats
  float* attnT = out + (size_t)kB * kD;           // [S, B] = 65536 floats

  float* ws      = (float*)d_ws;
  float* att     = ws;                                   // 65536
  float* attn_bs = ws + 65536;                           // 65536
  float* x       = ws + 131072;                          // 32768
  float* partial = ws + 163840;                          // 16*32*1024 = 524288
  float* cat     = ws + 688128;                          // 65536
  int*   s_count = (int*)(ws + 753664);                  // 32

  k_x<<<128, 256, 0, stream>>>(hidden, W1, x);
  k_att<<<kB * (kS / 16), 256, 0, stream>>>(enc, x, lens, att);
  k_softmax<<<kB, 256, 0, stream>>>(att, lens, attnT, attn_bs, s_count);
  k_ctx<<<kB * kNChunk, 256, 0, stream>>>(enc, attn_bs, s_count, partial);
  k_cat<<<kB * kK2 / 4 / 256, 256, 0, stream>>>(partial, hidden, s_count, cat);
  k_out<<<128, 256, 0, stream>>>(cat, W2, out);
}

// Round 2
// 89.423 us; speedup vs baseline: 1.4489x; 1.4489x over previous
//
#include <hip/hip_runtime.h>

namespace {
constexpr int kB = 32;
constexpr int kS = 2048;
constexpr int kH = 1024;
constexpr int kD = 1024;
constexpr int kK2 = kH + kD;           // 2048
constexpr int kSChunk = 32;
constexpr int kNChunk = kS / kSChunk;  // 64
constexpr float kWThresh = 1e-8f;      // sum of skipped weights <= 2048e-8 -> out err <= ~1e-3

__device__ inline float waveReduceSum(float v) {
#pragma unroll
  for (int off = 32; off > 0; off >>= 1) v += __shfl_down(v, off, 64);
  return v;
}
__device__ inline float waveReduceMax(float v) {
#pragma unroll
  for (int off = 32; off > 0; off >>= 1) v = fmaxf(v, __shfl_down(v, off, 64));
  return v;
}
}  // namespace

// x = hidden @ W1^T : [B, D]. Wave per 2 cols, b-split by 2 (grid 256 blocks).
__global__ __launch_bounds__(256) void k_x(const float* __restrict__ hidden,
                                           const float* __restrict__ W1,
                                           float* __restrict__ x) {
  const int wid = (blockIdx.x * blockDim.x + threadIdx.x) >> 6;  // 0..1023
  const int lane = threadIdx.x & 63;
  const int n0 = (wid & 511) * 2;
  const int b0 = (wid >> 9) * 16;
  const float4* w0v = (const float4*)(W1 + (size_t)n0 * kH);
  const float4* w1v = (const float4*)(W1 + (size_t)(n0 + 1) * kH);
  float4 w0[4], w1[4];
#pragma unroll
  for (int i = 0; i < 4; ++i) {
    w0[i] = w0v[lane + 64 * i];
    w1[i] = w1v[lane + 64 * i];
  }
  for (int b = b0; b < b0 + 16; ++b) {
    const float4* hv = (const float4*)(hidden + (size_t)b * kH);
    float a0 = 0.f, a1 = 0.f;
#pragma unroll
    for (int i = 0; i < 4; ++i) {
      const float4 h = hv[lane + 64 * i];
      a0 += w0[i].x * h.x + w0[i].y * h.y + w0[i].z * h.z + w0[i].w * h.w;
      a1 += w1[i].x * h.x + w1[i].y * h.y + w1[i].z * h.z + w1[i].w * h.w;
    }
    a0 = waveReduceSum(a0);
    a1 = waveReduceSum(a1);
    if (lane == 0) {
      x[(size_t)b * kD + n0] = a0;
      x[(size_t)b * kD + n0 + 1] = a1;
    }
  }
}

// att[b,s] = dot(enc[b,s,:], x[b,:]) for s < len[b]. Wave per 4 rows.
__global__ __launch_bounds__(256) void k_att(const float* __restrict__ enc,
                                             const float* __restrict__ x,
                                             const int* __restrict__ lens,
                                             float* __restrict__ att) {
  const int lane = threadIdx.x & 63;
  const int wib = threadIdx.x >> 6;
  const int b = blockIdx.x & 31;
  const int s0 = (blockIdx.x >> 5) * 16 + wib * 4;
  const int len = lens[b];
  if (s0 >= len) return;  // weight is exactly 0 -> never needed
  const float4* xv = (const float4*)(x + (size_t)b * kD);
  float4 xr[4];
#pragma unroll
  for (int i = 0; i < 4; ++i) xr[i] = xv[lane + 64 * i];
#pragma unroll
  for (int r = 0; r < 4; ++r) {
    const float4* ev = (const float4*)(enc + ((size_t)b * kS + (s0 + r)) * kD);
    float acc = 0.f;
#pragma unroll
    for (int i = 0; i < 4; ++i) {
      const float4 e = ev[lane + 64 * i];
      acc += xr[i].x * e.x + xr[i].y * e.y + xr[i].z * e.z + xr[i].w * e.w;
    }
    acc = waveReduceSum(acc);
    if (lane == 0) att[(size_t)b * kS + s0 + r] = acc;
  }
}

// Masked softmax per batch row, faithful to the ==0 -> -1e10 quirk.
// Writes attn^T into d_out, a coalesced [B][S] copy into ws, and s_count.
__global__ __launch_bounds__(256) void k_softmax(const float* __restrict__ att,
                                                 const int* __restrict__ lens,
                                                 float* __restrict__ attnT,
                                                 float* __restrict__ attn_bs,
                                                 int* __restrict__ s_count) {
  const int b = blockIdx.x;
  const int t = threadIdx.x;
  const int len = lens[b];
  __shared__ float sred[4];
  float v[8];
#pragma unroll
  for (int i = 0; i < 8; ++i) {
    const int s = t + i * 256;
    const float a = (s < len) ? att[(size_t)b * kS + s] : 0.0f;
    v[i] = (a == 0.0f) ? -1e10f : a;
  }
  float m = v[0];
#pragma unroll
  for (int i = 1; i < 8; ++i) m = fmaxf(m, v[i]);
  m = waveReduceMax(m);
  if ((t & 63) == 0) sred[t >> 6] = m;
  __syncthreads();
  m = fmaxf(fmaxf(sred[0], sred[1]), fmaxf(sred[2], sred[3]));
  __syncthreads();
  float p[8];
  float sum = 0.f;
#pragma unroll
  for (int i = 0; i < 8; ++i) {
    p[i] = __expf(v[i] - m);  // underflows to exactly 0 for masked rows
    sum += p[i];
  }
  sum = waveReduceSum(sum);
  if ((t & 63) == 0) sred[t >> 6] = sum;
  __syncthreads();
  const float inv = 1.0f / (sred[0] + sred[1] + sred[2] + sred[3]);
#pragma unroll
  for (int i = 0; i < 8; ++i) {
    const int s = t + i * 256;
    const float a = p[i] * inv;
    attnT[(size_t)s * kB + b] = a;          // output 1: attn^T [S][B]
    attn_bs[(size_t)b * kS + s] = a;        // coalesced copy for k_ctx
  }
  // degenerate case (all valid scores exactly 0): uniform over ALL S rows
  if (t == 0) s_count[b] = (m == -1e10f) ? kS : len;
}

// ctx partials with weight-skip: softmax is extremely peaked (score std ~32),
// so almost all weights are exactly 0.0f or < 1e-8. Skip those rows entirely.
__global__ __launch_bounds__(256) void k_ctx(const float* __restrict__ enc,
                                             const float* __restrict__ attn_bs,
                                             const int* __restrict__ s_count,
                                             float* __restrict__ partial) {
  const int b = blockIdx.x & 31;
  const int c = blockIdx.x >> 5;
  const int s0 = c * kSChunk;
  if (s0 >= s_count[b]) return;  // all weights in this chunk are exactly 0
  const int t = threadIdx.x;
  const float* wrow = attn_bs + (size_t)b * kS;
  float4 acc = make_float4(0.f, 0.f, 0.f, 0.f);
#pragma unroll
  for (int i = 0; i < kSChunk / 4; ++i) {
    const int s = s0 + i * 4;
    // weights beyond len are exactly 0 (exp underflow), so no bounds guard
    const float4 w4 = *(const float4*)(wrow + s);
    const float wm = fmaxf(fmaxf(w4.x, w4.y), fmaxf(w4.z, w4.w));
    if (wm <= kWThresh) continue;  // wave-uniform skip: no enc traffic
    const float4* ev = (const float4*)(enc + ((size_t)b * kS + s) * kD) + t;
    if (w4.x > kWThresh) {
      const float4 e = ev[0];
      acc.x += w4.x * e.x; acc.y += w4.x * e.y; acc.z += w4.x * e.z; acc.w += w4.x * e.w;
    }
    if (w4.y > kWThresh) {
      const float4 e = ev[256];
      acc.x += w4.y * e.x; acc.y += w4.y * e.y; acc.z += w4.y * e.z; acc.w += w4.y * e.w;
    }
    if (w4.z > kWThresh) {
      const float4 e = ev[512];
      acc.x += w4.z * e.x; acc.y += w4.z * e.y; acc.z += w4.z * e.z; acc.w += w4.z * e.w;
    }
    if (w4.w > kWThresh) {
      const float4 e = ev[768];
      acc.x += w4.w * e.x; acc.y += w4.w * e.y; acc.z += w4.w * e.z; acc.w += w4.w * e.w;
    }
  }
  ((float4*)(partial + ((size_t)c * kB + b) * kD))[t] = acc;
}

// cat[b, 0:D] = sum of valid ctx partials; cat[b, D:D+H] = hidden[b,:]
__global__ __launch_bounds__(256) void k_cat(const float* __restrict__ partial,
                                             const float* __restrict__ hidden,
                                             const int* __restrict__ s_count,
                                             float* __restrict__ cat) {
  const int idx = blockIdx.x * 256 + threadIdx.x;  // float4 index into [B][K2]
  const int b = idx >> 9;   // 512 float4 per row
  const int j = idx & 511;
  float4* dst = (float4*)(cat + (size_t)b * kK2);
  if (j < 256) {
    const int nch = (s_count[b] + kSChunk - 1) / kSChunk;
    float4 acc = make_float4(0.f, 0.f, 0.f, 0.f);
    for (int c = 0; c < nch; ++c) {
      const float4 p = ((const float4*)(partial + ((size_t)c * kB + b) * kD))[j];
      acc.x += p.x; acc.y += p.y; acc.z += p.z; acc.w += p.w;
    }
    dst[j] = acc;
  } else {
    dst[j] = ((const float4*)(hidden + (size_t)b * kH))[j - 256];
  }
}

// out = tanh(cat @ W2^T) : [B, D]. Wave per 2 cols, b-split by 2 (grid 256).
__global__ __launch_bounds__(256) void k_out(const float* __restrict__ cat,
                                             const float* __restrict__ W2,
                                             float* __restrict__ out) {
  const int wid = (blockIdx.x * blockDim.x + threadIdx.x) >> 6;  // 0..1023
  const int lane = threadIdx.x & 63;
  const int n0 = (wid & 511) * 2;
  const int b0 = (wid >> 9) * 16;
  const float4* w0v = (const float4*)(W2 + (size_t)n0 * kK2);
  const float4* w1v = (const float4*)(W2 + (size_t)(n0 + 1) * kK2);
  float4 w0[8], w1[8];
#pragma unroll
  for (int i = 0; i < 8; ++i) {
    w0[i] = w0v[lane + 64 * i];
    w1[i] = w1v[lane + 64 * i];
  }
  for (int b = b0; b < b0 + 16; ++b) {
    const float4* av = (const float4*)(cat + (size_t)b * kK2);
    float a0 = 0.f, a1 = 0.f;
#pragma unroll
    for (int i = 0; i < 8; ++i) {
      const float4 a = av[lane + 64 * i];
      a0 += w0[i].x * a.x + w0[i].y * a.y + w0[i].z * a.z + w0[i].w * a.w;
      a1 += w1[i].x * a.x + w1[i].y * a.y + w1[i].z * a.z + w1[i].w * a.w;
    }
    a0 = waveReduceSum(a0);
    a1 = waveReduceSum(a1);
    if (lane == 0) {
      out[(size_t)b * kD + n0] = tanhf(a0);
      out[(size_t)b * kD + n0 + 1] = tanhf(a1);
    }
  }
}

extern "C" void kernel_launch(void* const* d_in, const int* in_sizes, int n_in,
                              void* d_out, int out_size, void* d_ws, size_t ws_size,
                              hipStream_t stream) {
  const float* hidden = (const float*)d_in[0];    // [B, H]
  const float* enc    = (const float*)d_in[1];    // [B, S, D]
  const int*   lens   = (const int*)d_in[2];      // [B]
  const float* W1     = (const float*)d_in[3];    // [D, H]
  const float* W2     = (const float*)d_in[4];    // [D, H+D]

  float* out   = (float*)d_out;                   // [B, D] = 32768 floats
  float* attnT = out + (size_t)kB * kD;           // [S, B] = 65536 floats

  float* ws      = (float*)d_ws;
  float* att     = ws;                                   // 65536
  float* attn_bs = ws + 65536;                           // 65536
  float* x       = ws + 131072;                          // 32768
  float* partial = ws + 163840;                          // 64*32*1024 = 2097152
  float* cat     = ws + 2260992;                         // 65536
  int*   s_count = (int*)(ws + 2326528);                 // 32

  k_x<<<256, 256, 0, stream>>>(hidden, W1, x);
  k_att<<<kB * (kS / 16), 256, 0, stream>>>(enc, x, lens, att);
  k_softmax<<<kB, 256, 0, stream>>>(att, lens, attnT, attn_bs, s_count);
  k_ctx<<<kB * kNChunk, 256, 0, stream>>>(enc, attn_bs, s_count, partial);
  k_cat<<<kB * kK2 / 4 / 256, 256, 0, stream>>>(partial, hidden, s_count, cat);
  k_out<<<256, 256, 0, stream>>>(cat, W2, out);
}

// Round 4
// 67.153 us; speedup vs baseline: 1.9294x; 1.3316x over previous
//
#include <hip/hip_runtime.h>

namespace {
constexpr int kB = 32;
constexpr int kS = 2048;
constexpr int kH = 1024;
constexpr int kD = 1024;
constexpr int kK2 = kH + kD;           // 2048
constexpr float kWThresh = 1e-8f;      // skipped weight mass <= 2048e-8 -> out err ~1e-3 << 2e-2

typedef float f32x4 __attribute__((ext_vector_type(4)));  // clang-native, ok for nontemporal

__device__ inline float waveReduceSum(float v) {
#pragma unroll
  for (int off = 32; off > 0; off >>= 1) v += __shfl_down(v, off, 64);
  return v;
}
__device__ inline float waveReduceMax(float v) {
#pragma unroll
  for (int off = 32; off > 0; off >>= 1) v = fmaxf(v, __shfl_down(v, off, 64));
  return v;
}
}  // namespace

// x = hidden @ W1^T : [B, D]. Wave per 2 cols, b-split by 2 (grid 256 blocks).
__global__ __launch_bounds__(256) void k_x(const float* __restrict__ hidden,
                                           const float* __restrict__ W1,
                                           float* __restrict__ x) {
  const int wid = (blockIdx.x * blockDim.x + threadIdx.x) >> 6;  // 0..1023
  const int lane = threadIdx.x & 63;
  const int n0 = (wid & 511) * 2;
  const int b0 = (wid >> 9) * 16;
  const float4* w0v = (const float4*)(W1 + (size_t)n0 * kH);
  const float4* w1v = (const float4*)(W1 + (size_t)(n0 + 1) * kH);
  float4 w0[4], w1[4];
#pragma unroll
  for (int i = 0; i < 4; ++i) {
    w0[i] = w0v[lane + 64 * i];
    w1[i] = w1v[lane + 64 * i];
  }
  for (int b = b0; b < b0 + 16; ++b) {
    const float4* hv = (const float4*)(hidden + (size_t)b * kH);
    float a0 = 0.f, a1 = 0.f;
#pragma unroll
    for (int i = 0; i < 4; ++i) {
      const float4 h = hv[lane + 64 * i];
      a0 += w0[i].x * h.x + w0[i].y * h.y + w0[i].z * h.z + w0[i].w * h.w;
      a1 += w1[i].x * h.x + w1[i].y * h.y + w1[i].z * h.z + w1[i].w * h.w;
    }
    a0 = waveReduceSum(a0);
    a1 = waveReduceSum(a1);
    if (lane == 0) {
      x[(size_t)b * kD + n0] = a0;
      x[(size_t)b * kD + n0 + 1] = a1;
    }
  }
}

// att[b,s] = dot(enc[b,s,:], x[b,:]) for s < len[b]. Wave per 4 rows.
// enc is a 134 MB single-use stream -> non-temporal loads (keep L2 for x).
__global__ __launch_bounds__(256) void k_att(const float* __restrict__ enc,
                                             const float* __restrict__ x,
                                             const int* __restrict__ lens,
                                             float* __restrict__ att) {
  const int lane = threadIdx.x & 63;
  const int wib = threadIdx.x >> 6;
  const int b = blockIdx.x & 31;
  const int s0 = (blockIdx.x >> 5) * 16 + wib * 4;
  const int len = lens[b];
  if (s0 >= len) return;  // weight is exactly 0 -> never needed
  const f32x4* xv = (const f32x4*)(x + (size_t)b * kD);
  f32x4 xr[4];
#pragma unroll
  for (int i = 0; i < 4; ++i) xr[i] = xv[lane + 64 * i];
#pragma unroll
  for (int r = 0; r < 4; ++r) {
    const f32x4* ev = (const f32x4*)(enc + ((size_t)b * kS + (s0 + r)) * kD);
    float acc = 0.f;
#pragma unroll
    for (int i = 0; i < 4; ++i) {
      const f32x4 e = __builtin_nontemporal_load(&ev[lane + 64 * i]);
      acc += xr[i].x * e.x + xr[i].y * e.y + xr[i].z * e.z + xr[i].w * e.w;
    }
    acc = waveReduceSum(acc);
    if (lane == 0) att[(size_t)b * kS + s0 + r] = acc;
  }
}

// Fused masked-softmax (with ==0 -> -1e10 quirk) + weighted ctx, one block/batch.
// Thread t owns ctx[b][t]; survivors (w > 1e-8, typically ~4-8) gathered in LDS.
__global__ __launch_bounds__(1024) void k_smctx(const float* __restrict__ att,
                                                const int* __restrict__ lens,
                                                const float* __restrict__ enc,
                                                float* __restrict__ attnT,
                                                float* __restrict__ ctx) {
  const int b = blockIdx.x;
  const int t = threadIdx.x;
  const int len = lens[b];
  __shared__ float sred[16];
  __shared__ float swts[kS];
  __shared__ int sidx[kS];
  __shared__ int scount;

  const float a0 = (t < len) ? att[(size_t)b * kS + t] : 0.0f;
  const float a1 = (t + 1024 < len) ? att[(size_t)b * kS + t + 1024] : 0.0f;
  const float v0 = (a0 == 0.0f) ? -1e10f : a0;
  const float v1 = (a1 == 0.0f) ? -1e10f : a1;

  // block max
  float m = waveReduceMax(fmaxf(v0, v1));
  if ((t & 63) == 0) sred[t >> 6] = m;
  __syncthreads();
  if (t < 16) {
    float mm = sred[t];
#pragma unroll
    for (int off = 8; off > 0; off >>= 1) mm = fmaxf(mm, __shfl_down(mm, off, 64));
    if (t == 0) sred[0] = mm;
  }
  __syncthreads();
  m = sred[0];
  __syncthreads();

  // exp + block sum
  float p0 = __expf(v0 - m), p1 = __expf(v1 - m);
  float sum = waveReduceSum(p0 + p1);
  if ((t & 63) == 0) sred[t >> 6] = sum;
  __syncthreads();
  if (t < 16) {
    float ss = sred[t];
#pragma unroll
    for (int off = 8; off > 0; off >>= 1) ss += __shfl_down(ss, off, 64);
    if (t == 0) sred[0] = ss;
  }
  __syncthreads();
  const float inv = 1.0f / sred[0];
  p0 *= inv;
  p1 *= inv;

  // output 1: attn^T [S][B] (column write, 256 KB total across blocks)
  attnT[(size_t)t * kB + b] = p0;
  attnT[(size_t)(t + 1024) * kB + b] = p1;

  // survivor list
  if (t == 0) scount = 0;
  __syncthreads();
  if (p0 > kWThresh) { const int k = atomicAdd(&scount, 1); sidx[k] = t;        swts[k] = p0; }
  if (p1 > kWThresh) { const int k = atomicAdd(&scount, 1); sidx[k] = t + 1024; swts[k] = p1; }
  __syncthreads();

  // ctx[b][t] = sum over survivors w[s] * enc[b][s][t]  (coalesced 4 KB rows)
  const int n = scount;
  const float* ebase = enc + (size_t)b * kS * kD + t;
  float acc = 0.f;
  int k = 0;
  for (; k + 4 <= n; k += 4) {
    const float e0 = ebase[(size_t)sidx[k + 0] * kD];
    const float e1 = ebase[(size_t)sidx[k + 1] * kD];
    const float e2 = ebase[(size_t)sidx[k + 2] * kD];
    const float e3 = ebase[(size_t)sidx[k + 3] * kD];
    acc += swts[k + 0] * e0 + swts[k + 1] * e1 + swts[k + 2] * e2 + swts[k + 3] * e3;
  }
  for (; k < n; ++k) acc += swts[k] * ebase[(size_t)sidx[k] * kD];
  ctx[(size_t)b * kD + t] = acc;
}

// out = tanh([ctx | hidden] @ W2^T). Wave per 2 cols, b-split by 2 (grid 256).
__global__ __launch_bounds__(256) void k_out(const float* __restrict__ ctx,
                                             const float* __restrict__ hidden,
                                             const float* __restrict__ W2,
                                             float* __restrict__ out) {
  const int wid = (blockIdx.x * blockDim.x + threadIdx.x) >> 6;  // 0..1023
  const int lane = threadIdx.x & 63;
  const int n0 = (wid & 511) * 2;
  const int b0 = (wid >> 9) * 16;
  const float4* w0v = (const float4*)(W2 + (size_t)n0 * kK2);
  const float4* w1v = (const float4*)(W2 + (size_t)(n0 + 1) * kK2);
  float4 w0[8], w1[8];
#pragma unroll
  for (int i = 0; i < 8; ++i) {
    w0[i] = w0v[lane + 64 * i];
    w1[i] = w1v[lane + 64 * i];
  }
  for (int b = b0; b < b0 + 16; ++b) {
    const float4* cv = (const float4*)(ctx + (size_t)b * kD);
    const float4* hv = (const float4*)(hidden + (size_t)b * kH);
    float a0 = 0.f, a1 = 0.f;
#pragma unroll
    for (int i = 0; i < 4; ++i) {
      const float4 a = cv[lane + 64 * i];
      a0 += w0[i].x * a.x + w0[i].y * a.y + w0[i].z * a.z + w0[i].w * a.w;
      a1 += w1[i].x * a.x + w1[i].y * a.y + w1[i].z * a.z + w1[i].w * a.w;
    }
#pragma unroll
    for (int i = 0; i < 4; ++i) {
      const float4 h = hv[lane + 64 * i];
      a0 += w0[i + 4].x * h.x + w0[i + 4].y * h.y + w0[i + 4].z * h.z + w0[i + 4].w * h.w;
      a1 += w1[i + 4].x * h.x + w1[i + 4].y * h.y + w1[i + 4].z * h.z + w1[i + 4].w * h.w;
    }
    a0 = waveReduceSum(a0);
    a1 = waveReduceSum(a1);
    if (lane == 0) {
      out[(size_t)b * kD + n0] = tanhf(a0);
      out[(size_t)b * kD + n0 + 1] = tanhf(a1);
    }
  }
}

extern "C" void kernel_launch(void* const* d_in, const int* in_sizes, int n_in,
                              void* d_out, int out_size, void* d_ws, size_t ws_size,
                              hipStream_t stream) {
  const float* hidden = (const float*)d_in[0];    // [B, H]
  const float* enc    = (const float*)d_in[1];    // [B, S, D]
  const int*   lens   = (const int*)d_in[2];      // [B]
  const float* W1     = (const float*)d_in[3];    // [D, H]
  const float* W2     = (const float*)d_in[4];    // [D, H+D]

  float* out   = (float*)d_out;                   // [B, D] = 32768 floats
  float* attnT = out + (size_t)kB * kD;           // [S, B] = 65536 floats

  float* ws  = (float*)d_ws;
  float* att = ws;              // 65536
  float* x   = ws + 65536;      // 32768
  float* ctx = ws + 98304;      // 32768

  k_x<<<256, 256, 0, stream>>>(hidden, W1, x);
  k_att<<<kB * (kS / 16), 256, 0, stream>>>(enc, x, lens, att);
  k_smctx<<<kB, 1024, 0, stream>>>(att, lens, enc, attnT, ctx);
  k_out<<<256, 256, 0, stream>>>(ctx, hidden, W2, out);
}